// Round 1
// baseline (505.421 us; speedup 1.0000x reference)
//
#include <hip/hip_runtime.h>

// ChromaSelfAttention on MI355X (gfx950).
// Pipeline: cvt x->f16 | transpose-cvt W->W^T f16 | QKV GEMM (m97-style, MFMA f16)
//           | transpose V | flash attention (swizzled LDS) | output GEMM -> f32.
// All-fp16 operands with fp32 accumulation: error budget ~1.2e-3 vs threshold 2.578e-3.

typedef _Float16 f16;
typedef __attribute__((ext_vector_type(8))) _Float16 f16x8;
typedef __attribute__((ext_vector_type(4))) _Float16 f16x4;
typedef __attribute__((ext_vector_type(4))) float f32x4;

#define LOG2E 1.4426950408889634f
#define ATT_SCALE 0.08838834764831845f  // 128^-0.5

static __device__ __forceinline__ void gload16(void* lds, const void* g) {
  __builtin_amdgcn_global_load_lds(
      (__attribute__((address_space(1))) void*)g,
      (__attribute__((address_space(3))) void*)lds, 16, 0, 0);
}

// ---------------- fp32 -> fp16 conversion of x_q/x_k/x_v (z selects) -------
__global__ __launch_bounds__(256) void cvt_x_kernel(
    const float* __restrict__ x0, const float* __restrict__ x1,
    const float* __restrict__ x2, f16* __restrict__ out) {
  const float* x = blockIdx.z == 0 ? x0 : (blockIdx.z == 1 ? x1 : x2);
  f16* o = out + (size_t)blockIdx.z * 8388608;
  size_t i = ((size_t)blockIdx.x * 256 + threadIdx.x) * 8;
  f32x4 a = *(const f32x4*)(x + i);
  f32x4 b = *(const f32x4*)(x + i + 4);
  f16x8 r;
  r[0] = (f16)a[0]; r[1] = (f16)a[1]; r[2] = (f16)a[2]; r[3] = (f16)a[3];
  r[4] = (f16)b[0]; r[5] = (f16)b[1]; r[6] = (f16)b[2]; r[7] = (f16)b[3];
  *(f16x8*)(o + i) = r;
}

// -------- W [K=2048][N=2048] f32 -> W^T [N][K] f16 (z: Wq,Wk,Wv,Wo) --------
__global__ __launch_bounds__(256) void cvt_w_kernel(
    const float* __restrict__ w0, const float* __restrict__ w1,
    const float* __restrict__ w2, const float* __restrict__ w3,
    f16* __restrict__ out) {
  const float* W = blockIdx.z == 0 ? w0 : blockIdx.z == 1 ? w1
                 : blockIdx.z == 2 ? w2 : w3;
  f16* WT = out + (size_t)blockIdx.z * 4194304;
  __shared__ f16 tile[64][68];  // +4 pad
  const int tx = threadIdx.x & 15, ty = threadIdx.x >> 4;
  const int k0 = blockIdx.y * 64, n0 = blockIdx.x * 64;
#pragma unroll
  for (int i = 0; i < 4; ++i) {
    int r = ty + i * 16;  // local k
    f32x4 v = *(const f32x4*)(W + (size_t)(k0 + r) * 2048 + n0 + tx * 4);
    tile[r][tx * 4 + 0] = (f16)v[0]; tile[r][tx * 4 + 1] = (f16)v[1];
    tile[r][tx * 4 + 2] = (f16)v[2]; tile[r][tx * 4 + 3] = (f16)v[3];
  }
  __syncthreads();
#pragma unroll
  for (int i = 0; i < 4; ++i) {
    int n = ty + i * 16;  // local n
    f16x4 o;
    o[0] = tile[tx * 4 + 0][n]; o[1] = tile[tx * 4 + 1][n];
    o[2] = tile[tx * 4 + 2][n]; o[3] = tile[tx * 4 + 3][n];
    *(f16x4*)(WT + (size_t)(n0 + n) * 2048 + k0 + tx * 4) = o;
  }
}

// ---------------- QKV projection GEMM: C = A[4096,2048] @ Bt[2048,2048]^T --
// m97 structure: 128x128 tile, BK=32, 4 waves (2x2), global_load_lds w=16.
// Epilogue: head-split f16 out [b,h,l,d] + bias.
__global__ __launch_bounds__(256) void gemm_qkv_kernel(
    const f16* __restrict__ Abase, const f16* __restrict__ Btbase,
    f16* __restrict__ Obase, const float* __restrict__ b0,
    const float* __restrict__ b1, const float* __restrict__ b2) {
  const int z = blockIdx.z;
  const f16* A  = Abase  + (size_t)z * 8388608;
  const f16* Bt = Btbase + (size_t)z * 4194304;
  f16* Oz = Obase + (size_t)z * 8388608;
  const float* bias = z == 0 ? b0 : z == 1 ? b1 : b2;
  const int tid = threadIdx.x, lane = tid & 63, w = tid >> 6;
  const int wm = w >> 1, wn = w & 1;
  const int bm = blockIdx.y, bn = blockIdx.x;
  const int l15 = lane & 15, lg = lane >> 4;
  __shared__ alignas(16) f16 As[128 * 32];
  __shared__ alignas(16) f16 Bs[128 * 32];
  f32x4 acc[4][4];
#pragma unroll
  for (int i = 0; i < 4; ++i)
#pragma unroll
    for (int j = 0; j < 4; ++j) acc[i][j] = (f32x4)0.f;

  for (int kt = 0; kt < 64; ++kt) {
    __syncthreads();
#pragma unroll
    for (int i = 0; i < 2; ++i) {
      int c = i * 4 + w;
      int phys = c * 1024 + lane * 16;
      int row = phys >> 6, colb = phys & 63;
      gload16((char*)As + c * 1024,
              (const char*)A + ((size_t)(bm * 128 + row) * 2048 + kt * 32) * 2 + colb);
      gload16((char*)Bs + c * 1024,
              (const char*)Bt + ((size_t)(bn * 128 + row) * 2048 + kt * 32) * 2 + colb);
    }
    __syncthreads();
    f16x8 af[4], bf[4];
#pragma unroll
    for (int i = 0; i < 4; ++i)
      af[i] = *(const f16x8*)(As + (wm * 64 + i * 16 + l15) * 32 + lg * 8);
#pragma unroll
    for (int j = 0; j < 4; ++j)
      bf[j] = *(const f16x8*)(Bs + (wn * 64 + j * 16 + l15) * 32 + lg * 8);
#pragma unroll
    for (int i = 0; i < 4; ++i)
#pragma unroll
      for (int j = 0; j < 4; ++j)
        acc[i][j] = __builtin_amdgcn_mfma_f32_16x16x32_f16(af[i], bf[j], acc[i][j], 0, 0, 0);
  }
#pragma unroll
  for (int i = 0; i < 4; ++i)
#pragma unroll
    for (int j = 0; j < 4; ++j) {
      int col = bn * 128 + wn * 64 + j * 16 + l15;
      int h = col >> 7, d = col & 127;
      float bv = bias[col];
#pragma unroll
      for (int r = 0; r < 4; ++r) {
        int rowg = bm * 128 + wm * 64 + i * 16 + lg * 4 + r;
        int b_ = rowg >> 11, lpos = rowg & 2047;
        Oz[(size_t)(b_ * 16 + h) * 262144 + (size_t)lpos * 128 + d] =
            (f16)(acc[i][j][r] + bv);
      }
    }
}

// ---------------- output GEMM: d_out = O[4096,2048] @ WoT^T + bo (fp32) ----
__global__ __launch_bounds__(256) void gemm_out_kernel(
    const f16* __restrict__ A, const f16* __restrict__ Bt,
    float* __restrict__ Out, const float* __restrict__ bias) {
  const int tid = threadIdx.x, lane = tid & 63, w = tid >> 6;
  const int wm = w >> 1, wn = w & 1;
  const int bm = blockIdx.y, bn = blockIdx.x;
  const int l15 = lane & 15, lg = lane >> 4;
  __shared__ alignas(16) f16 As[128 * 32];
  __shared__ alignas(16) f16 Bs[128 * 32];
  f32x4 acc[4][4];
#pragma unroll
  for (int i = 0; i < 4; ++i)
#pragma unroll
    for (int j = 0; j < 4; ++j) acc[i][j] = (f32x4)0.f;

  for (int kt = 0; kt < 64; ++kt) {
    __syncthreads();
#pragma unroll
    for (int i = 0; i < 2; ++i) {
      int c = i * 4 + w;
      int phys = c * 1024 + lane * 16;
      int row = phys >> 6, colb = phys & 63;
      gload16((char*)As + c * 1024,
              (const char*)A + ((size_t)(bm * 128 + row) * 2048 + kt * 32) * 2 + colb);
      gload16((char*)Bs + c * 1024,
              (const char*)Bt + ((size_t)(bn * 128 + row) * 2048 + kt * 32) * 2 + colb);
    }
    __syncthreads();
    f16x8 af[4], bf[4];
#pragma unroll
    for (int i = 0; i < 4; ++i)
      af[i] = *(const f16x8*)(As + (wm * 64 + i * 16 + l15) * 32 + lg * 8);
#pragma unroll
    for (int j = 0; j < 4; ++j)
      bf[j] = *(const f16x8*)(Bs + (wn * 64 + j * 16 + l15) * 32 + lg * 8);
#pragma unroll
    for (int i = 0; i < 4; ++i)
#pragma unroll
      for (int j = 0; j < 4; ++j)
        acc[i][j] = __builtin_amdgcn_mfma_f32_16x16x32_f16(af[i], bf[j], acc[i][j], 0, 0, 0);
  }
#pragma unroll
  for (int i = 0; i < 4; ++i)
#pragma unroll
    for (int j = 0; j < 4; ++j) {
      int col = bn * 128 + wn * 64 + j * 16 + l15;
      float bv = bias[col];
#pragma unroll
      for (int r = 0; r < 4; ++r) {
        int rowg = bm * 128 + wm * 64 + i * 16 + lg * 4 + r;
        Out[(size_t)rowg * 2048 + col] = acc[i][j][r] + bv;
      }
    }
}

// ---------------- V [b,h,l,128] -> V^T [b,h,128,L] (f16) -------------------
__global__ __launch_bounds__(256) void tr_v_kernel(const f16* __restrict__ v,
                                                   f16* __restrict__ vtout) {
  const int bh = blockIdx.z;
  const f16* V = v + (size_t)bh * 262144;
  f16* VT = vtout + (size_t)bh * 262144;
  __shared__ f16 tile[64][68];
  const int tx = threadIdx.x & 15, ty = threadIdx.x >> 4;
  const int l0 = blockIdx.x * 64, d0 = blockIdx.y * 64;
#pragma unroll
  for (int i = 0; i < 4; ++i) {
    int r = ty + i * 16;  // local l
    f16x4 val = *(const f16x4*)(V + (size_t)(l0 + r) * 128 + d0 + tx * 4);
    tile[r][tx * 4 + 0] = val[0]; tile[r][tx * 4 + 1] = val[1];
    tile[r][tx * 4 + 2] = val[2]; tile[r][tx * 4 + 3] = val[3];
  }
  __syncthreads();
#pragma unroll
  for (int i = 0; i < 4; ++i) {
    int d = ty + i * 16;  // local d
    f16x4 o;
    o[0] = tile[tx * 4 + 0][d]; o[1] = tile[tx * 4 + 1][d];
    o[2] = tile[tx * 4 + 2][d]; o[3] = tile[tx * 4 + 3][d];
    *(f16x4*)(VT + (size_t)(d0 + d) * 2048 + l0 + tx * 4) = o;
  }
}

// ---------------- flash attention ------------------------------------------
// Block: 4 waves, Q-tile 128 rows (32/wave), KVBLK=64, online softmax.
// K/V^T staged via global_load_lds with XOR-swizzled source; P via swizzled LDS.
__global__ __launch_bounds__(256) void attn_kernel(
    const f16* __restrict__ q, const f16* __restrict__ k,
    const f16* __restrict__ vt, f16* __restrict__ o) {
  const int bh = blockIdx.y, qt = blockIdx.x;
  const int tid = threadIdx.x, lane = tid & 63, w = tid >> 6;
  const int l15 = lane & 15, lg = lane >> 4;
  const f16* Qb = q + (size_t)bh * 262144 + (size_t)qt * 128 * 128;
  const char* Kb = (const char*)(k + (size_t)bh * 262144);
  const char* Vtb = (const char*)(vt + (size_t)bh * 262144);
  __shared__ alignas(16) char sm[49152];
  char* Ks = sm;           // [64 kv][256B d] swizzled
  char* Vs = sm + 16384;   // [128 d][128B kv] swizzled
  char* Ps = sm + 32768;   // [128 m][128B kv] swizzled

  f16x8 qf[2][4];
#pragma unroll
  for (int mf = 0; mf < 2; ++mf)
#pragma unroll
    for (int ks = 0; ks < 4; ++ks)
      qf[mf][ks] = *(const f16x8*)(Qb + (w * 32 + mf * 16 + l15) * 128 + ks * 32 + lg * 8);

  f32x4 oacc[2][8];
  float mrow[2][4], lrow[2][4];
#pragma unroll
  for (int mf = 0; mf < 2; ++mf) {
#pragma unroll
    for (int df = 0; df < 8; ++df) oacc[mf][df] = (f32x4)0.f;
#pragma unroll
    for (int r = 0; r < 4; ++r) { mrow[mf][r] = -1e30f; lrow[mf][r] = 0.f; }
  }

  for (int t = 0; t < 32; ++t) {
    __syncthreads();  // previous tile fully consumed
#pragma unroll
    for (int i = 0; i < 4; ++i) {  // stage K tile [64][256B]
      int c = i * 4 + w;
      int phys = c * 1024 + lane * 16;
      int row = phys >> 8, pcol = phys & 255;
      int lcol = pcol ^ ((row & 7) << 4);
      gload16(Ks + c * 1024, Kb + (size_t)(t * 64 + row) * 256 + lcol);
    }
#pragma unroll
    for (int i = 0; i < 4; ++i) {  // stage V^T tile [128][128B]
      int c = i * 4 + w;
      int phys = c * 1024 + lane * 16;
      int row = phys >> 7, pcol = phys & 127;
      int lcol = pcol ^ ((row & 7) << 4);
      gload16(Vs + c * 1024, Vtb + (size_t)row * 4096 + t * 128 + lcol);
    }
    __syncthreads();  // staging complete (vmcnt drained by barrier)

    // QK^T -> s[2][4] (m 32 x n 64 per wave)
    f32x4 s[2][4];
#pragma unroll
    for (int mf = 0; mf < 2; ++mf)
#pragma unroll
      for (int nf = 0; nf < 4; ++nf) s[mf][nf] = (f32x4)0.f;
#pragma unroll
    for (int ks = 0; ks < 4; ++ks) {
      f16x8 bf[4];
#pragma unroll
      for (int nf = 0; nf < 4; ++nf) {
        int row = nf * 16 + l15;
        int colb = ks * 64 + lg * 16;
        bf[nf] = *(const f16x8*)(Ks + row * 256 + (colb ^ ((row & 7) << 4)));
      }
#pragma unroll
      for (int mf = 0; mf < 2; ++mf)
#pragma unroll
        for (int nf = 0; nf < 4; ++nf)
          s[mf][nf] = __builtin_amdgcn_mfma_f32_16x16x32_f16(qf[mf][ks], bf[nf], s[mf][nf], 0, 0, 0);
    }
#pragma unroll
    for (int mf = 0; mf < 2; ++mf)
#pragma unroll
      for (int nf = 0; nf < 4; ++nf) s[mf][nf] *= ATT_SCALE;

    // online softmax; write P (f16) into swizzled Ps
#pragma unroll
    for (int mf = 0; mf < 2; ++mf) {
#pragma unroll
      for (int r = 0; r < 4; ++r) {
        float mx = fmaxf(fmaxf(s[mf][0][r], s[mf][1][r]),
                         fmaxf(s[mf][2][r], s[mf][3][r]));
        mx = fmaxf(mx, __shfl_xor(mx, 1));
        mx = fmaxf(mx, __shfl_xor(mx, 2));
        mx = fmaxf(mx, __shfl_xor(mx, 4));
        mx = fmaxf(mx, __shfl_xor(mx, 8));
        float mold = mrow[mf][r];
        float mnew = fmaxf(mold, mx);
        mrow[mf][r] = mnew;
        float sc = exp2f((mold - mnew) * LOG2E);
        lrow[mf][r] *= sc;
#pragma unroll
        for (int df = 0; df < 8; ++df) oacc[mf][df][r] *= sc;
        float psum = 0.f;
        int prow = w * 32 + mf * 16 + lg * 4 + r;
#pragma unroll
        for (int nf = 0; nf < 4; ++nf) {
          float p = exp2f((s[mf][nf][r] - mnew) * LOG2E);
          psum += p;
          int pcolb = (nf * 16 + l15) * 2;
          *(f16*)(Ps + prow * 128 + (pcolb ^ ((prow & 7) << 4))) = (f16)p;
        }
        psum += __shfl_xor(psum, 1);
        psum += __shfl_xor(psum, 2);
        psum += __shfl_xor(psum, 4);
        psum += __shfl_xor(psum, 8);
        lrow[mf][r] += psum;
      }
    }
    __syncthreads();  // P visible (same-wave cross-lane + keeps waves in phase)

    // PV: oacc += P[32 x 64] @ V[64 x 128]
#pragma unroll
    for (int kvs = 0; kvs < 2; ++kvs) {
      f16x8 pa[2];
#pragma unroll
      for (int mf = 0; mf < 2; ++mf) {
        int row = w * 32 + mf * 16 + l15;
        int colb = kvs * 64 + lg * 16;
        pa[mf] = *(const f16x8*)(Ps + row * 128 + (colb ^ ((row & 7) << 4)));
      }
#pragma unroll
      for (int df = 0; df < 8; ++df) {
        int row = df * 16 + l15;
        int colb = kvs * 64 + lg * 16;
        f16x8 vb = *(const f16x8*)(Vs + row * 128 + (colb ^ ((row & 7) << 4)));
#pragma unroll
        for (int mf = 0; mf < 2; ++mf)
          oacc[mf][df] = __builtin_amdgcn_mfma_f32_16x16x32_f16(pa[mf], vb, oacc[mf][df], 0, 0, 0);
      }
    }
  }

  // epilogue: normalize, write o [b,l,h*128+d] f16
  const int b_ = bh >> 4, h_ = bh & 15;
  f16* Ob = o + (size_t)b_ * 2048 * 2048 + (size_t)qt * 128 * 2048 + h_ * 128;
#pragma unroll
  for (int mf = 0; mf < 2; ++mf)
#pragma unroll
    for (int r = 0; r < 4; ++r) {
      float inv = 1.f / lrow[mf][r];
      int rl = w * 32 + mf * 16 + lg * 4 + r;
#pragma unroll
      for (int df = 0; df < 8; ++df)
        Ob[(size_t)rl * 2048 + df * 16 + l15] = (f16)(oacc[mf][df][r] * inv);
    }
}

// ---------------------------------------------------------------------------
extern "C" void kernel_launch(void* const* d_in, const int* in_sizes, int n_in,
                              void* d_out, int out_size, void* d_ws, size_t ws_size,
                              hipStream_t stream) {
  const float* xq = (const float*)d_in[0];
  const float* xk = (const float*)d_in[1];
  const float* xv = (const float*)d_in[2];
  const float* Wq = (const float*)d_in[3];
  const float* bq = (const float*)d_in[4];
  const float* Wk = (const float*)d_in[5];
  const float* bk = (const float*)d_in[6];
  const float* Wv = (const float*)d_in[7];
  const float* bv = (const float*)d_in[8];
  const float* Wo = (const float*)d_in[9];
  const float* bo = (const float*)d_in[10];

  // ws layout (bytes), total 128 MiB:
  //   [0,50331648)        xh: x_q/x_k/x_v f16 (3 x 16 MiB)
  //   [50331648,83886080) wt: WqT/WkT/WvT/WoT f16 (4 x 8 MiB)
  //   [83886080,134217728) qkv: q/k/v head-split f16 (3 x 16 MiB)
  //   vT aliases xh_q slot (dead after QKV GEMM); o aliases xh_k slot.
  char* ws = (char*)d_ws;
  f16* xh   = (f16*)(ws);
  f16* wt   = (f16*)(ws + 50331648);
  f16* qkv  = (f16*)(ws + 83886080);
  f16* vtb  = (f16*)(ws);             // alias: x_q f16 region
  f16* oatt = (f16*)(ws + 16777216);  // alias: x_k f16 region
  float* outp = (float*)d_out;

  hipLaunchKernelGGL(cvt_x_kernel, dim3(4096, 1, 3), dim3(256), 0, stream,
                     xq, xk, xv, xh);
  hipLaunchKernelGGL(cvt_w_kernel, dim3(32, 32, 4), dim3(256), 0, stream,
                     Wq, Wk, Wv, Wo, wt);
  hipLaunchKernelGGL(gemm_qkv_kernel, dim3(16, 32, 3), dim3(256), 0, stream,
                     xh, wt, qkv, bq, bk, bv);
  hipLaunchKernelGGL(tr_v_kernel, dim3(32, 2, 32), dim3(256), 0, stream,
                     qkv + (size_t)2 * 8388608, vtb);
  hipLaunchKernelGGL(attn_kernel, dim3(16, 32), dim3(256), 0, stream,
                     qkv, qkv + (size_t)8388608, vtb, oatt);
  hipLaunchKernelGGL(gemm_out_kernel, dim3(16, 32), dim3(256), 0, stream,
                     oatt, wt + (size_t)3 * 4194304, outp, bo);
}

// Round 2
// 363.317 us; speedup vs baseline: 1.3911x; 1.3911x over previous
//
#include <hip/hip_runtime.h>

// ChromaSelfAttention on MI355X (gfx950).
// Pipeline: cvt x->f16 | transpose-cvt W->W^T f16 | QKV GEMM (m97-style, MFMA f16)
//           | transpose V | flash attention (swapped QK^T, register P, dbuf LDS)
//           | output GEMM -> f32.
// fp16 operands, fp32 accumulation. Softmax scale*log2e folded into Q projection.

typedef _Float16 f16;
typedef __attribute__((ext_vector_type(8))) _Float16 f16x8;
typedef __attribute__((ext_vector_type(4))) _Float16 f16x4;
typedef __attribute__((ext_vector_type(4))) float f32x4;
typedef __attribute__((ext_vector_type(4))) unsigned int u32x4;

#define QSCALE (0.08838834764831845f * 1.4426950408889634f)  // d^-0.5 * log2(e)
#define SWZ3(r) (((r) & 3) | (((r) >> 1) & 4))               // 3-bit row swizzle

static __device__ __forceinline__ void gload16(void* lds, const void* g) {
  __builtin_amdgcn_global_load_lds(
      (__attribute__((address_space(1))) void*)g,
      (__attribute__((address_space(3))) void*)lds, 16, 0, 0);
}

// ---------------- fp32 -> fp16 conversion of x_q/x_k/x_v (z selects) -------
__global__ __launch_bounds__(256) void cvt_x_kernel(
    const float* __restrict__ x0, const float* __restrict__ x1,
    const float* __restrict__ x2, f16* __restrict__ out) {
  const float* x = blockIdx.z == 0 ? x0 : (blockIdx.z == 1 ? x1 : x2);
  f16* o = out + (size_t)blockIdx.z * 8388608;
  size_t i = ((size_t)blockIdx.x * 256 + threadIdx.x) * 8;
  f32x4 a = *(const f32x4*)(x + i);
  f32x4 b = *(const f32x4*)(x + i + 4);
  f16x8 r;
  r[0] = (f16)a[0]; r[1] = (f16)a[1]; r[2] = (f16)a[2]; r[3] = (f16)a[3];
  r[4] = (f16)b[0]; r[5] = (f16)b[1]; r[6] = (f16)b[2]; r[7] = (f16)b[3];
  *(f16x8*)(o + i) = r;
}

// -------- W [K=2048][N=2048] f32 -> W^T [N][K] f16 (z: Wq,Wk,Wv,Wo) --------
__global__ __launch_bounds__(256) void cvt_w_kernel(
    const float* __restrict__ w0, const float* __restrict__ w1,
    const float* __restrict__ w2, const float* __restrict__ w3,
    f16* __restrict__ out) {
  const float* W = blockIdx.z == 0 ? w0 : blockIdx.z == 1 ? w1
                 : blockIdx.z == 2 ? w2 : w3;
  f16* WT = out + (size_t)blockIdx.z * 4194304;
  __shared__ f16 tile[64][68];  // +4 pad
  const int tx = threadIdx.x & 15, ty = threadIdx.x >> 4;
  const int k0 = blockIdx.y * 64, n0 = blockIdx.x * 64;
#pragma unroll
  for (int i = 0; i < 4; ++i) {
    int r = ty + i * 16;  // local k
    f32x4 v = *(const f32x4*)(W + (size_t)(k0 + r) * 2048 + n0 + tx * 4);
    tile[r][tx * 4 + 0] = (f16)v[0]; tile[r][tx * 4 + 1] = (f16)v[1];
    tile[r][tx * 4 + 2] = (f16)v[2]; tile[r][tx * 4 + 3] = (f16)v[3];
  }
  __syncthreads();
#pragma unroll
  for (int i = 0; i < 4; ++i) {
    int n = ty + i * 16;  // local n
    f16x4 o;
    o[0] = tile[tx * 4 + 0][n]; o[1] = tile[tx * 4 + 1][n];
    o[2] = tile[tx * 4 + 2][n]; o[3] = tile[tx * 4 + 3][n];
    *(f16x4*)(WT + (size_t)(n0 + n) * 2048 + k0 + tx * 4) = o;
  }
}

// ---------------- QKV projection GEMM: C = A[4096,2048] @ Bt[2048,2048]^T --
// Epilogue: head-split f16 out [b,h,l,d] + bias; z==0 (Q) scaled by QSCALE.
__global__ __launch_bounds__(256) void gemm_qkv_kernel(
    const f16* __restrict__ Abase, const f16* __restrict__ Btbase,
    f16* __restrict__ Obase, const float* __restrict__ b0,
    const float* __restrict__ b1, const float* __restrict__ b2) {
  const int z = blockIdx.z;
  const f16* A  = Abase  + (size_t)z * 8388608;
  const f16* Bt = Btbase + (size_t)z * 4194304;
  f16* Oz = Obase + (size_t)z * 8388608;
  const float* bias = z == 0 ? b0 : z == 1 ? b1 : b2;
  const float qsc = z == 0 ? QSCALE : 1.0f;
  const int tid = threadIdx.x, lane = tid & 63, w = tid >> 6;
  const int wm = w >> 1, wn = w & 1;
  const int bm = blockIdx.y, bn = blockIdx.x;
  const int l15 = lane & 15, lg = lane >> 4;
  __shared__ alignas(16) f16 As[128 * 32];
  __shared__ alignas(16) f16 Bs[128 * 32];
  f32x4 acc[4][4];
#pragma unroll
  for (int i = 0; i < 4; ++i)
#pragma unroll
    for (int j = 0; j < 4; ++j) acc[i][j] = (f32x4)0.f;

  for (int kt = 0; kt < 64; ++kt) {
    __syncthreads();
#pragma unroll
    for (int i = 0; i < 2; ++i) {
      int c = i * 4 + w;
      int phys = c * 1024 + lane * 16;
      int row = phys >> 6, colb = phys & 63;
      gload16((char*)As + c * 1024,
              (const char*)A + ((size_t)(bm * 128 + row) * 2048 + kt * 32) * 2 + colb);
      gload16((char*)Bs + c * 1024,
              (const char*)Bt + ((size_t)(bn * 128 + row) * 2048 + kt * 32) * 2 + colb);
    }
    __syncthreads();
    f16x8 af[4], bf[4];
#pragma unroll
    for (int i = 0; i < 4; ++i)
      af[i] = *(const f16x8*)(As + (wm * 64 + i * 16 + l15) * 32 + lg * 8);
#pragma unroll
    for (int j = 0; j < 4; ++j)
      bf[j] = *(const f16x8*)(Bs + (wn * 64 + j * 16 + l15) * 32 + lg * 8);
#pragma unroll
    for (int i = 0; i < 4; ++i)
#pragma unroll
      for (int j = 0; j < 4; ++j)
        acc[i][j] = __builtin_amdgcn_mfma_f32_16x16x32_f16(af[i], bf[j], acc[i][j], 0, 0, 0);
  }
#pragma unroll
  for (int i = 0; i < 4; ++i)
#pragma unroll
    for (int j = 0; j < 4; ++j) {
      int col = bn * 128 + wn * 64 + j * 16 + l15;
      int h = col >> 7, d = col & 127;
      float bv = bias[col];
#pragma unroll
      for (int r = 0; r < 4; ++r) {
        int rowg = bm * 128 + wm * 64 + i * 16 + lg * 4 + r;
        int b_ = rowg >> 11, lpos = rowg & 2047;
        Oz[(size_t)(b_ * 16 + h) * 262144 + (size_t)lpos * 128 + d] =
            (f16)((acc[i][j][r] + bv) * qsc);
      }
    }
}

// ---------------- output GEMM: d_out = O[4096,2048] @ WoT^T + bo (fp32) ----
__global__ __launch_bounds__(256) void gemm_out_kernel(
    const f16* __restrict__ A, const f16* __restrict__ Bt,
    float* __restrict__ Out, const float* __restrict__ bias) {
  const int tid = threadIdx.x, lane = tid & 63, w = tid >> 6;
  const int wm = w >> 1, wn = w & 1;
  const int bm = blockIdx.y, bn = blockIdx.x;
  const int l15 = lane & 15, lg = lane >> 4;
  __shared__ alignas(16) f16 As[128 * 32];
  __shared__ alignas(16) f16 Bs[128 * 32];
  f32x4 acc[4][4];
#pragma unroll
  for (int i = 0; i < 4; ++i)
#pragma unroll
    for (int j = 0; j < 4; ++j) acc[i][j] = (f32x4)0.f;

  for (int kt = 0; kt < 64; ++kt) {
    __syncthreads();
#pragma unroll
    for (int i = 0; i < 2; ++i) {
      int c = i * 4 + w;
      int phys = c * 1024 + lane * 16;
      int row = phys >> 6, colb = phys & 63;
      gload16((char*)As + c * 1024,
              (const char*)A + ((size_t)(bm * 128 + row) * 2048 + kt * 32) * 2 + colb);
      gload16((char*)Bs + c * 1024,
              (const char*)Bt + ((size_t)(bn * 128 + row) * 2048 + kt * 32) * 2 + colb);
    }
    __syncthreads();
    f16x8 af[4], bf[4];
#pragma unroll
    for (int i = 0; i < 4; ++i)
      af[i] = *(const f16x8*)(As + (wm * 64 + i * 16 + l15) * 32 + lg * 8);
#pragma unroll
    for (int j = 0; j < 4; ++j)
      bf[j] = *(const f16x8*)(Bs + (wn * 64 + j * 16 + l15) * 32 + lg * 8);
#pragma unroll
    for (int i = 0; i < 4; ++i)
#pragma unroll
      for (int j = 0; j < 4; ++j)
        acc[i][j] = __builtin_amdgcn_mfma_f32_16x16x32_f16(af[i], bf[j], acc[i][j], 0, 0, 0);
  }
#pragma unroll
  for (int i = 0; i < 4; ++i)
#pragma unroll
    for (int j = 0; j < 4; ++j) {
      int col = bn * 128 + wn * 64 + j * 16 + l15;
      float bv = bias[col];
#pragma unroll
      for (int r = 0; r < 4; ++r) {
        int rowg = bm * 128 + wm * 64 + i * 16 + lg * 4 + r;
        Out[(size_t)rowg * 2048 + col] = acc[i][j][r] + bv;
      }
    }
}

// ---------------- V [b,h,l,128] -> V^T [b,h,128,L] (f16) -------------------
__global__ __launch_bounds__(256) void tr_v_kernel(const f16* __restrict__ v,
                                                   f16* __restrict__ vtout) {
  const int bh = blockIdx.z;
  const f16* V = v + (size_t)bh * 262144;
  f16* VT = vtout + (size_t)bh * 262144;
  __shared__ f16 tile[64][68];
  const int tx = threadIdx.x & 15, ty = threadIdx.x >> 4;
  const int l0 = blockIdx.x * 64, d0 = blockIdx.y * 64;
#pragma unroll
  for (int i = 0; i < 4; ++i) {
    int r = ty + i * 16;  // local l
    f16x4 val = *(const f16x4*)(V + (size_t)(l0 + r) * 128 + d0 + tx * 4);
    tile[r][tx * 4 + 0] = val[0]; tile[r][tx * 4 + 1] = val[1];
    tile[r][tx * 4 + 2] = val[2]; tile[r][tx * 4 + 3] = val[3];
  }
  __syncthreads();
#pragma unroll
  for (int i = 0; i < 4; ++i) {
    int d = ty + i * 16;  // local d
    f16x4 o;
    o[0] = tile[tx * 4 + 0][d]; o[1] = tile[tx * 4 + 1][d];
    o[2] = tile[tx * 4 + 2][d]; o[3] = tile[tx * 4 + 3][d];
    *(f16x4*)(VT + (size_t)(d0 + d) * 2048 + l0 + tx * 4) = o;
  }
}

// ---------------- flash attention (swapped QK^T, register P) ---------------
// 4 waves x 32 q-rows, KVBLK=64, double-buffered K/V LDS, 1 barrier/tile.
// S = mfma(K,Q): each lane owns q-row (lane&15) per mf frag. K rows permuted
// per-fragment so packed P lands directly in PV's A-fragment layout.
__global__ __launch_bounds__(256) void attn_kernel(
    const f16* __restrict__ q, const f16* __restrict__ k,
    const f16* __restrict__ vt, f16* __restrict__ o) {
  const int bh = blockIdx.y, qt = blockIdx.x;
  const int tid = threadIdx.x, lane = tid & 63, w = tid >> 6;
  const int l15 = lane & 15, lg = lane >> 4;
  const f16* Qb = q + (size_t)bh * 262144 + (size_t)qt * 128 * 128;
  const char* Kb = (const char*)(k + (size_t)bh * 262144);
  const char* Vtb = (const char*)(vt + (size_t)bh * 262144);
  __shared__ alignas(16) char sm[65536];  // buf b: K @ b*32768 (16K), V @ +16384 (16K)

  // Q fragments (B-operand): rows w*32+mf*16+l15, k = ks*32 + lg*8 (+0..7)
  f16x8 qf[2][4];
#pragma unroll
  for (int mf = 0; mf < 2; ++mf)
#pragma unroll
    for (int ks = 0; ks < 4; ++ks)
      qf[mf][ks] = *(const f16x8*)(Qb + (w * 32 + mf * 16 + l15) * 128 + ks * 32 + lg * 8);

  f32x4 oacc[2][8];
  float mrow[2], lrow[2];
#pragma unroll
  for (int mf = 0; mf < 2; ++mf) {
#pragma unroll
    for (int df = 0; df < 8; ++df) oacc[mf][df] = (f32x4)0.f;
    mrow[mf] = -1e30f; lrow[mf] = 0.f;
  }

  const int rA = ((l15 >> 2) << 3) + (l15 & 3);  // K-frag row permutation base

#define STAGE(T, B)                                                          \
  {                                                                          \
    char* Ks_ = sm + (B) * 32768;                                            \
    char* Vs_ = Ks_ + 16384;                                                 \
    _Pragma("unroll") for (int i = 0; i < 4; ++i) {                          \
      int c = i * 4 + w;                                                     \
      int phys = c * 1024 + lane * 16;                                       \
      {                                                                      \
        int row = phys >> 8, pcol = phys & 255;                              \
        int lcol = pcol ^ (SWZ3(row) << 4);                                  \
        gload16(Ks_ + c * 1024, Kb + (size_t)((T) * 64 + row) * 256 + lcol); \
      }                                                                      \
      {                                                                      \
        int row = phys >> 7, pcol = phys & 127;                              \
        int lcol = pcol ^ (SWZ3(row) << 4);                                  \
        gload16(Vs_ + c * 1024, Vtb + (size_t)row * 4096 + (T) * 128 + lcol);\
      }                                                                      \
    }                                                                        \
  }

  STAGE(0, 0);
  int cur = 0;
  for (int t = 0; t < 32; ++t) {
    __syncthreads();  // drains vmcnt(0): buf[cur] staged; all waves done with buf[cur^1]
    if (t < 31) STAGE(t + 1, cur ^ 1);  // overlaps with compute below
    const char* Ks = sm + cur * 32768;
    const char* Vs = Ks + 16384;

    // ---- QK^T swapped: s[mf][nf] = S[kv'][q] -------------------------------
    f32x4 s[2][4];
#pragma unroll
    for (int mf = 0; mf < 2; ++mf)
#pragma unroll
      for (int nf = 0; nf < 4; ++nf) s[mf][nf] = (f32x4)0.f;
#pragma unroll
    for (int ks = 0; ks < 4; ++ks) {
      f16x8 kf[4];
#pragma unroll
      for (int nf = 0; nf < 4; ++nf) {
        int row = ((nf & 1) << 5) + ((nf >> 1) << 2) + rA;  // permuted kv row
        int colb = (ks * 64 + lg * 16) ^ (SWZ3(row) << 4);
        kf[nf] = *(const f16x8*)(Ks + row * 256 + colb);
      }
#pragma unroll
      for (int mf = 0; mf < 2; ++mf)
#pragma unroll
        for (int nf = 0; nf < 4; ++nf)
          s[mf][nf] = __builtin_amdgcn_mfma_f32_16x16x32_f16(kf[nf], qf[mf][ks], s[mf][nf], 0, 0, 0);
    }
    // lane (l15,lg) holds, for q-row w*32+mf*16+l15:
    //   kv = (nf&1)*32 + lg*8 + (nf>>1)*4 + r   (16 of 64 scores; log2 units)

    // ---- online softmax, P packed in registers -----------------------------
    unsigned int pkk[2][4][2];
    float scm[2];
#pragma unroll
    for (int mf = 0; mf < 2; ++mf) {
      float mx = s[mf][0][0];
#pragma unroll
      for (int nf = 0; nf < 4; ++nf)
#pragma unroll
        for (int r = 0; r < 4; ++r) mx = fmaxf(mx, s[mf][nf][r]);
      mx = fmaxf(mx, __shfl_xor(mx, 16));
      mx = fmaxf(mx, __shfl_xor(mx, 32));
      float mnew = fmaxf(mrow[mf], mx);
      float sc = exp2f(mrow[mf] - mnew);
      float psum = 0.f;
#pragma unroll
      for (int nf = 0; nf < 4; ++nf)
#pragma unroll
        for (int h = 0; h < 2; ++h) {
          float p0 = exp2f(s[mf][nf][2 * h] - mnew);
          float p1 = exp2f(s[mf][nf][2 * h + 1] - mnew);
          psum += p0 + p1;
          pkk[mf][nf][h] =
              __builtin_bit_cast(unsigned int, __builtin_amdgcn_cvt_pkrtz(p0, p1));
        }
      psum += __shfl_xor(psum, 16);
      psum += __shfl_xor(psum, 32);
      lrow[mf] = lrow[mf] * sc + psum;
      mrow[mf] = mnew;
      scm[mf] = sc;
    }
    // rescale oacc: its rows are q = lg*4+r, stats live at lane l15==row
#pragma unroll
    for (int mf = 0; mf < 2; ++mf)
#pragma unroll
      for (int r = 0; r < 4; ++r) {
        float scr = __shfl(scm[mf], (lane & 48) | (lg * 4 + r));
#pragma unroll
        for (int df = 0; df < 8; ++df) oacc[mf][df][r] *= scr;
      }

    // ---- PV: oacc += P[32 x 64] @ V[64 x 128] ------------------------------
#pragma unroll
    for (int kvs = 0; kvs < 2; ++kvs) {
      f16x8 pa[2];
#pragma unroll
      for (int mf = 0; mf < 2; ++mf) {
        u32x4 av;
        av[0] = pkk[mf][kvs][0];     av[1] = pkk[mf][kvs][1];
        av[2] = pkk[mf][2 + kvs][0]; av[3] = pkk[mf][2 + kvs][1];
        pa[mf] = __builtin_bit_cast(f16x8, av);
      }
#pragma unroll
      for (int df = 0; df < 8; ++df) {
        int row = df * 16 + l15;
        int colb = (kvs * 64 + lg * 16) ^ (SWZ3(row) << 4);
        f16x8 vb = *(const f16x8*)(Vs + row * 128 + colb);
#pragma unroll
        for (int mf = 0; mf < 2; ++mf)
          oacc[mf][df] = __builtin_amdgcn_mfma_f32_16x16x32_f16(pa[mf], vb, oacc[mf][df], 0, 0, 0);
      }
    }
    cur ^= 1;
  }

  // epilogue: normalize, write o [b,l,h*128+d] f16
  const int b_ = bh >> 4, h_ = bh & 15;
  f16* Ob = o + (size_t)b_ * 2048 * 2048 + (size_t)qt * 128 * 2048 + h_ * 128;
#pragma unroll
  for (int mf = 0; mf < 2; ++mf) {
    float inv = 1.f / lrow[mf];  // for q-row l15
#pragma unroll
    for (int r = 0; r < 4; ++r) {
      float invr = __shfl(inv, (lane & 48) | (lg * 4 + r));
      int rl = w * 32 + mf * 16 + lg * 4 + r;
#pragma unroll
      for (int df = 0; df < 8; ++df)
        Ob[(size_t)rl * 2048 + df * 16 + l15] = (f16)(oacc[mf][df][r] * invr);
    }
  }
#undef STAGE
}

// ---------------------------------------------------------------------------
extern "C" void kernel_launch(void* const* d_in, const int* in_sizes, int n_in,
                              void* d_out, int out_size, void* d_ws, size_t ws_size,
                              hipStream_t stream) {
  const float* xq = (const float*)d_in[0];
  const float* xk = (const float*)d_in[1];
  const float* xv = (const float*)d_in[2];
  const float* Wq = (const float*)d_in[3];
  const float* bq = (const float*)d_in[4];
  const float* Wk = (const float*)d_in[5];
  const float* bk = (const float*)d_in[6];
  const float* Wv = (const float*)d_in[7];
  const float* bv = (const float*)d_in[8];
  const float* Wo = (const float*)d_in[9];
  const float* bo = (const float*)d_in[10];

  // ws layout (bytes), total 128 MiB:
  //   [0,50331648)        xh: x_q/x_k/x_v f16 (3 x 16 MiB)
  //   [50331648,83886080) wt: WqT/WkT/WvT/WoT f16 (4 x 8 MiB)
  //   [83886080,134217728) qkv: q/k/v head-split f16 (3 x 16 MiB)
  //   vT aliases xh_q slot (dead after QKV GEMM); o aliases xh_k slot.
  char* ws = (char*)d_ws;
  f16* xh   = (f16*)(ws);
  f16* wt   = (f16*)(ws + 50331648);
  f16* qkv  = (f16*)(ws + 83886080);
  f16* vtb  = (f16*)(ws);             // alias: x_q f16 region
  f16* oatt = (f16*)(ws + 16777216);  // alias: x_k f16 region
  float* outp = (float*)d_out;

  hipLaunchKernelGGL(cvt_x_kernel, dim3(4096, 1, 3), dim3(256), 0, stream,
                     xq, xk, xv, xh);
  hipLaunchKernelGGL(cvt_w_kernel, dim3(32, 32, 4), dim3(256), 0, stream,
                     Wq, Wk, Wv, Wo, wt);
  hipLaunchKernelGGL(gemm_qkv_kernel, dim3(16, 32, 3), dim3(256), 0, stream,
                     xh, wt, qkv, bq, bk, bv);
  hipLaunchKernelGGL(tr_v_kernel, dim3(32, 2, 32), dim3(256), 0, stream,
                     qkv + (size_t)2 * 8388608, vtb);
  hipLaunchKernelGGL(attn_kernel, dim3(16, 32), dim3(256), 0, stream,
                     qkv, qkv + (size_t)8388608, vtb, oatt);
  hipLaunchKernelGGL(gemm_out_kernel, dim3(16, 32), dim3(256), 0, stream,
                     oatt, wt + (size_t)3 * 4194304, outp, bo);
}

// Round 3
// 349.676 us; speedup vs baseline: 1.4454x; 1.0390x over previous
//
#include <hip/hip_runtime.h>

// ChromaSelfAttention on MI355X (gfx950).
// Pipeline: cvt x->f16 | transpose-cvt W->W^T f16 | QKV GEMM (m97-style, MFMA f16)
//           | transpose V | flash attention (swapped QK^T, register P, dbuf LDS,
//           defer-max, deferred l-reduce, setprio) | output GEMM -> f32.
// fp16 operands, fp32 accumulation. Softmax scale*log2(e) folded into Q projection.

typedef _Float16 f16;
typedef __attribute__((ext_vector_type(8))) _Float16 f16x8;
typedef __attribute__((ext_vector_type(4))) _Float16 f16x4;
typedef __attribute__((ext_vector_type(4))) float f32x4;
typedef __attribute__((ext_vector_type(4))) unsigned int u32x4;

#define QSCALE (0.08838834764831845f * 1.4426950408889634f)  // d^-0.5 * log2(e)
#define SWZ3(r) (((r) & 3) | (((r) >> 1) & 4))  // K-tile swizzle (rows jump 0-3,8-11,..)
#define SWZV(r) ((r) & 7)                       // V-tile swizzle (rows consecutive)

static __device__ __forceinline__ void gload16(void* lds, const void* g) {
  __builtin_amdgcn_global_load_lds(
      (__attribute__((address_space(1))) void*)g,
      (__attribute__((address_space(3))) void*)lds, 16, 0, 0);
}

// ---------------- fp32 -> fp16 conversion of x_q/x_k/x_v (z selects) -------
__global__ __launch_bounds__(256) void cvt_x_kernel(
    const float* __restrict__ x0, const float* __restrict__ x1,
    const float* __restrict__ x2, f16* __restrict__ out) {
  const float* x = blockIdx.z == 0 ? x0 : (blockIdx.z == 1 ? x1 : x2);
  f16* o = out + (size_t)blockIdx.z * 8388608;
  size_t i = ((size_t)blockIdx.x * 256 + threadIdx.x) * 8;
  f32x4 a = *(const f32x4*)(x + i);
  f32x4 b = *(const f32x4*)(x + i + 4);
  f16x8 r;
  r[0] = (f16)a[0]; r[1] = (f16)a[1]; r[2] = (f16)a[2]; r[3] = (f16)a[3];
  r[4] = (f16)b[0]; r[5] = (f16)b[1]; r[6] = (f16)b[2]; r[7] = (f16)b[3];
  *(f16x8*)(o + i) = r;
}

// -------- W [K=2048][N=2048] f32 -> W^T [N][K] f16 (z: Wq,Wk,Wv,Wo) --------
__global__ __launch_bounds__(256) void cvt_w_kernel(
    const float* __restrict__ w0, const float* __restrict__ w1,
    const float* __restrict__ w2, const float* __restrict__ w3,
    f16* __restrict__ out) {
  const float* W = blockIdx.z == 0 ? w0 : blockIdx.z == 1 ? w1
                 : blockIdx.z == 2 ? w2 : w3;
  f16* WT = out + (size_t)blockIdx.z * 4194304;
  __shared__ f16 tile[64][68];  // +4 pad
  const int tx = threadIdx.x & 15, ty = threadIdx.x >> 4;
  const int k0 = blockIdx.y * 64, n0 = blockIdx.x * 64;
#pragma unroll
  for (int i = 0; i < 4; ++i) {
    int r = ty + i * 16;  // local k
    f32x4 v = *(const f32x4*)(W + (size_t)(k0 + r) * 2048 + n0 + tx * 4);
    tile[r][tx * 4 + 0] = (f16)v[0]; tile[r][tx * 4 + 1] = (f16)v[1];
    tile[r][tx * 4 + 2] = (f16)v[2]; tile[r][tx * 4 + 3] = (f16)v[3];
  }
  __syncthreads();
#pragma unroll
  for (int i = 0; i < 4; ++i) {
    int n = ty + i * 16;  // local n
    f16x4 o;
    o[0] = tile[tx * 4 + 0][n]; o[1] = tile[tx * 4 + 1][n];
    o[2] = tile[tx * 4 + 2][n]; o[3] = tile[tx * 4 + 3][n];
    *(f16x4*)(WT + (size_t)(n0 + n) * 2048 + k0 + tx * 4) = o;
  }
}

// ---------------- QKV projection GEMM: C = A[4096,2048] @ Bt[2048,2048]^T --
// Epilogue: head-split f16 out [b,h,l,d] + bias; z==0 (Q) scaled by QSCALE.
__global__ __launch_bounds__(256) void gemm_qkv_kernel(
    const f16* __restrict__ Abase, const f16* __restrict__ Btbase,
    f16* __restrict__ Obase, const float* __restrict__ b0,
    const float* __restrict__ b1, const float* __restrict__ b2) {
  const int z = blockIdx.z;
  const f16* A  = Abase  + (size_t)z * 8388608;
  const f16* Bt = Btbase + (size_t)z * 4194304;
  f16* Oz = Obase + (size_t)z * 8388608;
  const float* bias = z == 0 ? b0 : z == 1 ? b1 : b2;
  const float qsc = z == 0 ? QSCALE : 1.0f;
  const int tid = threadIdx.x, lane = tid & 63, w = tid >> 6;
  const int wm = w >> 1, wn = w & 1;
  const int bm = blockIdx.y, bn = blockIdx.x;
  const int l15 = lane & 15, lg = lane >> 4;
  __shared__ alignas(16) f16 As[128 * 32];
  __shared__ alignas(16) f16 Bs[128 * 32];
  f32x4 acc[4][4];
#pragma unroll
  for (int i = 0; i < 4; ++i)
#pragma unroll
    for (int j = 0; j < 4; ++j) acc[i][j] = (f32x4)0.f;

  for (int kt = 0; kt < 64; ++kt) {
    __syncthreads();
#pragma unroll
    for (int i = 0; i < 2; ++i) {
      int c = i * 4 + w;
      int phys = c * 1024 + lane * 16;
      int row = phys >> 6, colb = phys & 63;
      gload16((char*)As + c * 1024,
              (const char*)A + ((size_t)(bm * 128 + row) * 2048 + kt * 32) * 2 + colb);
      gload16((char*)Bs + c * 1024,
              (const char*)Bt + ((size_t)(bn * 128 + row) * 2048 + kt * 32) * 2 + colb);
    }
    __syncthreads();
    f16x8 af[4], bf[4];
#pragma unroll
    for (int i = 0; i < 4; ++i)
      af[i] = *(const f16x8*)(As + (wm * 64 + i * 16 + l15) * 32 + lg * 8);
#pragma unroll
    for (int j = 0; j < 4; ++j)
      bf[j] = *(const f16x8*)(Bs + (wn * 64 + j * 16 + l15) * 32 + lg * 8);
#pragma unroll
    for (int i = 0; i < 4; ++i)
#pragma unroll
      for (int j = 0; j < 4; ++j)
        acc[i][j] = __builtin_amdgcn_mfma_f32_16x16x32_f16(af[i], bf[j], acc[i][j], 0, 0, 0);
  }
#pragma unroll
  for (int i = 0; i < 4; ++i)
#pragma unroll
    for (int j = 0; j < 4; ++j) {
      int col = bn * 128 + wn * 64 + j * 16 + l15;
      int h = col >> 7, d = col & 127;
      float bv = bias[col];
#pragma unroll
      for (int r = 0; r < 4; ++r) {
        int rowg = bm * 128 + wm * 64 + i * 16 + lg * 4 + r;
        int b_ = rowg >> 11, lpos = rowg & 2047;
        Oz[(size_t)(b_ * 16 + h) * 262144 + (size_t)lpos * 128 + d] =
            (f16)((acc[i][j][r] + bv) * qsc);
      }
    }
}

// ---------------- output GEMM: d_out = O[4096,2048] @ WoT^T + bo (fp32) ----
__global__ __launch_bounds__(256) void gemm_out_kernel(
    const f16* __restrict__ A, const f16* __restrict__ Bt,
    float* __restrict__ Out, const float* __restrict__ bias) {
  const int tid = threadIdx.x, lane = tid & 63, w = tid >> 6;
  const int wm = w >> 1, wn = w & 1;
  const int bm = blockIdx.y, bn = blockIdx.x;
  const int l15 = lane & 15, lg = lane >> 4;
  __shared__ alignas(16) f16 As[128 * 32];
  __shared__ alignas(16) f16 Bs[128 * 32];
  f32x4 acc[4][4];
#pragma unroll
  for (int i = 0; i < 4; ++i)
#pragma unroll
    for (int j = 0; j < 4; ++j) acc[i][j] = (f32x4)0.f;

  for (int kt = 0; kt < 64; ++kt) {
    __syncthreads();
#pragma unroll
    for (int i = 0; i < 2; ++i) {
      int c = i * 4 + w;
      int phys = c * 1024 + lane * 16;
      int row = phys >> 6, colb = phys & 63;
      gload16((char*)As + c * 1024,
              (const char*)A + ((size_t)(bm * 128 + row) * 2048 + kt * 32) * 2 + colb);
      gload16((char*)Bs + c * 1024,
              (const char*)Bt + ((size_t)(bn * 128 + row) * 2048 + kt * 32) * 2 + colb);
    }
    __syncthreads();
    f16x8 af[4], bf[4];
#pragma unroll
    for (int i = 0; i < 4; ++i)
      af[i] = *(const f16x8*)(As + (wm * 64 + i * 16 + l15) * 32 + lg * 8);
#pragma unroll
    for (int j = 0; j < 4; ++j)
      bf[j] = *(const f16x8*)(Bs + (wn * 64 + j * 16 + l15) * 32 + lg * 8);
#pragma unroll
    for (int i = 0; i < 4; ++i)
#pragma unroll
      for (int j = 0; j < 4; ++j)
        acc[i][j] = __builtin_amdgcn_mfma_f32_16x16x32_f16(af[i], bf[j], acc[i][j], 0, 0, 0);
  }
#pragma unroll
  for (int i = 0; i < 4; ++i)
#pragma unroll
    for (int j = 0; j < 4; ++j) {
      int col = bn * 128 + wn * 64 + j * 16 + l15;
      float bv = bias[col];
#pragma unroll
      for (int r = 0; r < 4; ++r) {
        int rowg = bm * 128 + wm * 64 + i * 16 + lg * 4 + r;
        Out[(size_t)rowg * 2048 + col] = acc[i][j][r] + bv;
      }
    }
}

// ---------------- V [b,h,l,128] -> V^T [b,h,128,L] (f16) -------------------
__global__ __launch_bounds__(256) void tr_v_kernel(const f16* __restrict__ v,
                                                   f16* __restrict__ vtout) {
  const int bh = blockIdx.z;
  const f16* V = v + (size_t)bh * 262144;
  f16* VT = vtout + (size_t)bh * 262144;
  __shared__ f16 tile[64][68];
  const int tx = threadIdx.x & 15, ty = threadIdx.x >> 4;
  const int l0 = blockIdx.x * 64, d0 = blockIdx.y * 64;
#pragma unroll
  for (int i = 0; i < 4; ++i) {
    int r = ty + i * 16;  // local l
    f16x4 val = *(const f16x4*)(V + (size_t)(l0 + r) * 128 + d0 + tx * 4);
    tile[r][tx * 4 + 0] = val[0]; tile[r][tx * 4 + 1] = val[1];
    tile[r][tx * 4 + 2] = val[2]; tile[r][tx * 4 + 3] = val[3];
  }
  __syncthreads();
#pragma unroll
  for (int i = 0; i < 4; ++i) {
    int d = ty + i * 16;  // local d
    f16x4 o;
    o[0] = tile[tx * 4 + 0][d]; o[1] = tile[tx * 4 + 1][d];
    o[2] = tile[tx * 4 + 2][d]; o[3] = tile[tx * 4 + 3][d];
    *(f16x4*)(VT + (size_t)(d0 + d) * 2048 + l0 + tx * 4) = o;
  }
}

// ---------------- flash attention (swapped QK^T, register P) ---------------
// 4 waves x 32 q-rows, KVBLK=64, double-buffered K/V LDS, 1 barrier/tile.
// S = mfma(K,Q): lane owns q-row (lane&15). K rows permuted per-fragment so
// packed P lands directly in PV's A-fragment layout (zero shuffle).
// Defer-max (THR=8) skips rescale most tiles; l-reduction deferred to epilogue.
__global__ __launch_bounds__(256) void attn_kernel(
    const f16* __restrict__ q, const f16* __restrict__ k,
    const f16* __restrict__ vt, f16* __restrict__ o) {
  const int bh = blockIdx.y, qt = blockIdx.x;
  const int tid = threadIdx.x, lane = tid & 63, w = tid >> 6;
  const int l15 = lane & 15, lg = lane >> 4;
  const f16* Qb = q + (size_t)bh * 262144 + (size_t)qt * 128 * 128;
  const char* Kb = (const char*)(k + (size_t)bh * 262144);
  const char* Vtb = (const char*)(vt + (size_t)bh * 262144);
  __shared__ alignas(16) char sm[65536];  // buf b: K @ b*32768 (16K), V @ +16384 (16K)

  // Q fragments (B-operand): rows w*32+mf*16+l15, k = ks*32 + lg*8 (+0..7)
  f16x8 qf[2][4];
#pragma unroll
  for (int mf = 0; mf < 2; ++mf)
#pragma unroll
    for (int ks = 0; ks < 4; ++ks)
      qf[mf][ks] = *(const f16x8*)(Qb + (w * 32 + mf * 16 + l15) * 128 + ks * 32 + lg * 8);

  f32x4 oacc[2][8];
  float mrow[2], ps[2];
#pragma unroll
  for (int mf = 0; mf < 2; ++mf) {
#pragma unroll
    for (int df = 0; df < 8; ++df) oacc[mf][df] = (f32x4)0.f;
    mrow[mf] = -1e30f; ps[mf] = 0.f;
  }

  const int rA = ((l15 >> 2) << 3) + (l15 & 3);  // K-frag row permutation base

#define STAGE(T, B)                                                          \
  {                                                                          \
    char* Ks_ = sm + (B) * 32768;                                            \
    char* Vs_ = Ks_ + 16384;                                                 \
    _Pragma("unroll") for (int i = 0; i < 4; ++i) {                          \
      int c = i * 4 + w;                                                     \
      int phys = c * 1024 + lane * 16;                                       \
      {                                                                      \
        int row = phys >> 8, pcol = phys & 255;                              \
        int lcol = pcol ^ (SWZ3(row) << 4);                                  \
        gload16(Ks_ + c * 1024, Kb + (size_t)((T) * 64 + row) * 256 + lcol); \
      }                                                                      \
      {                                                                      \
        int row = phys >> 7, pcol = phys & 127;                              \
        int lcol = pcol ^ (SWZV(row) << 4);                                  \
        gload16(Vs_ + c * 1024, Vtb + (size_t)row * 4096 + (T) * 128 + lcol);\
      }                                                                      \
    }                                                                        \
  }

  STAGE(0, 0);
  int cur = 0;
  for (int t = 0; t < 32; ++t) {
    __syncthreads();  // drains vmcnt: buf[cur] staged; all waves done with buf[cur^1]
    if (t < 31) STAGE(t + 1, cur ^ 1);  // overlaps with compute below
    const char* Ks = sm + cur * 32768;
    const char* Vs = Ks + 16384;

    // ---- QK^T swapped: s[mf][nf] = S[kv'][q] -------------------------------
    f32x4 s[2][4];
#pragma unroll
    for (int mf = 0; mf < 2; ++mf)
#pragma unroll
      for (int nf = 0; nf < 4; ++nf) s[mf][nf] = (f32x4)0.f;
    __builtin_amdgcn_s_setprio(1);
#pragma unroll
    for (int ks = 0; ks < 4; ++ks) {
      f16x8 kf[4];
#pragma unroll
      for (int nf = 0; nf < 4; ++nf) {
        int row = ((nf & 1) << 5) + ((nf >> 1) << 2) + rA;  // permuted kv row
        int colb = (ks * 64 + lg * 16) ^ (SWZ3(row) << 4);
        kf[nf] = *(const f16x8*)(Ks + row * 256 + colb);
      }
#pragma unroll
      for (int mf = 0; mf < 2; ++mf)
#pragma unroll
        for (int nf = 0; nf < 4; ++nf)
          s[mf][nf] = __builtin_amdgcn_mfma_f32_16x16x32_f16(kf[nf], qf[mf][ks], s[mf][nf], 0, 0, 0);
    }
    __builtin_amdgcn_s_setprio(0);
    // lane (l15,lg) reg r of s[mf][nf] = S[kv=(nf&1)*32+lg*8+(nf>>1)*4+r][q-row l15]
    // (in log2 units: QSCALE folded into Q)

    // ---- online softmax (defer-max), P packed in registers -----------------
    unsigned int pk[2][2][4];  // [mf][kvs][word] -> PV A-frag direct
#pragma unroll
    for (int mf = 0; mf < 2; ++mf) {
      float m01 = fmaxf(fmaxf(s[mf][0][0], s[mf][0][1]),
                        fmaxf(s[mf][0][2], s[mf][0][3]));
      float m23 = fmaxf(fmaxf(s[mf][1][0], s[mf][1][1]),
                        fmaxf(s[mf][1][2], s[mf][1][3]));
      float m45 = fmaxf(fmaxf(s[mf][2][0], s[mf][2][1]),
                        fmaxf(s[mf][2][2], s[mf][2][3]));
      float m67 = fmaxf(fmaxf(s[mf][3][0], s[mf][3][1]),
                        fmaxf(s[mf][3][2], s[mf][3][3]));
      float mx = fmaxf(fmaxf(m01, m23), fmaxf(m45, m67));
      mx = fmaxf(mx, __shfl_xor(mx, 16));
      mx = fmaxf(mx, __shfl_xor(mx, 32));
      if (!__all(mx <= mrow[mf] + 8.f)) {  // rare after first tile
        float mnew = fmaxf(mrow[mf], mx);
        float sc = exp2f(mrow[mf] - mnew);
        mrow[mf] = mnew;
        ps[mf] *= sc;
#pragma unroll
        for (int r = 0; r < 4; ++r) {
          float scr = __shfl(sc, (lane & 48) | (lg * 4 + r));
#pragma unroll
          for (int df = 0; df < 8; ++df) oacc[mf][df][r] *= scr;
        }
      }
      float m = mrow[mf];
      float psum = 0.f;
#pragma unroll
      for (int nf = 0; nf < 4; ++nf)
#pragma unroll
        for (int h = 0; h < 2; ++h) {
          float p0 = exp2f(s[mf][nf][2 * h] - m);
          float p1 = exp2f(s[mf][nf][2 * h + 1] - m);
          psum += p0 + p1;
          pk[mf][nf & 1][(nf >> 1) * 2 + h] =
              __builtin_bit_cast(unsigned int, __builtin_amdgcn_cvt_pkrtz(p0, p1));
        }
      ps[mf] += psum;  // cross-lane reduction deferred to epilogue
    }

    // ---- PV: oacc += P[32 x 64] @ V[64 x 128] ------------------------------
    __builtin_amdgcn_s_setprio(1);
#pragma unroll
    for (int kvs = 0; kvs < 2; ++kvs) {
      f16x8 pa[2];
#pragma unroll
      for (int mf = 0; mf < 2; ++mf)
        pa[mf] = __builtin_bit_cast(f16x8, *(const u32x4*)pk[mf][kvs]);
#pragma unroll
      for (int df = 0; df < 8; ++df) {
        int row = df * 16 + l15;
        int colb = (kvs * 64 + lg * 16) ^ (SWZV(row) << 4);
        f16x8 vb = *(const f16x8*)(Vs + row * 128 + colb);
#pragma unroll
        for (int mf = 0; mf < 2; ++mf)
          oacc[mf][df] = __builtin_amdgcn_mfma_f32_16x16x32_f16(pa[mf], vb, oacc[mf][df], 0, 0, 0);
      }
    }
    __builtin_amdgcn_s_setprio(0);
    cur ^= 1;
  }

  // epilogue: reduce l across lanes, normalize, write o [b,l,h*128+d] f16
  const int b_ = bh >> 4, h_ = bh & 15;
  f16* Ob = o + (size_t)b_ * 2048 * 2048 + (size_t)qt * 128 * 2048 + h_ * 128;
#pragma unroll
  for (int mf = 0; mf < 2; ++mf) {
    float lr = ps[mf];
    lr += __shfl_xor(lr, 16);
    lr += __shfl_xor(lr, 32);
    float inv = 1.f / lr;  // for q-row l15
#pragma unroll
    for (int r = 0; r < 4; ++r) {
      float invr = __shfl(inv, (lane & 48) | (lg * 4 + r));
      int rl = w * 32 + mf * 16 + lg * 4 + r;
#pragma unroll
      for (int df = 0; df < 8; ++df)
        Ob[(size_t)rl * 2048 + df * 16 + l15] = (f16)(oacc[mf][df][r] * invr);
    }
  }
#undef STAGE
}

// ---------------------------------------------------------------------------
extern "C" void kernel_launch(void* const* d_in, const int* in_sizes, int n_in,
                              void* d_out, int out_size, void* d_ws, size_t ws_size,
                              hipStream_t stream) {
  const float* xq = (const float*)d_in[0];
  const float* xk = (const float*)d_in[1];
  const float* xv = (const float*)d_in[2];
  const float* Wq = (const float*)d_in[3];
  const float* bq = (const float*)d_in[4];
  const float* Wk = (const float*)d_in[5];
  const float* bk = (const float*)d_in[6];
  const float* Wv = (const float*)d_in[7];
  const float* bv = (const float*)d_in[8];
  const float* Wo = (const float*)d_in[9];
  const float* bo = (const float*)d_in[10];

  // ws layout (bytes), total 128 MiB:
  //   [0,50331648)        xh: x_q/x_k/x_v f16 (3 x 16 MiB)
  //   [50331648,83886080) wt: WqT/WkT/WvT/WoT f16 (4 x 8 MiB)
  //   [83886080,134217728) qkv: q/k/v head-split f16 (3 x 16 MiB)
  //   vT aliases xh_q slot (dead after QKV GEMM); o aliases xh_k slot.
  char* ws = (char*)d_ws;
  f16* xh   = (f16*)(ws);
  f16* wt   = (f16*)(ws + 50331648);
  f16* qkv  = (f16*)(ws + 83886080);
  f16* vtb  = (f16*)(ws);             // alias: x_q f16 region
  f16* oatt = (f16*)(ws + 16777216);  // alias: x_k f16 region
  float* outp = (float*)d_out;

  hipLaunchKernelGGL(cvt_x_kernel, dim3(4096, 1, 3), dim3(256), 0, stream,
                     xq, xk, xv, xh);
  hipLaunchKernelGGL(cvt_w_kernel, dim3(32, 32, 4), dim3(256), 0, stream,
                     Wq, Wk, Wv, Wo, wt);
  hipLaunchKernelGGL(gemm_qkv_kernel, dim3(16, 32, 3), dim3(256), 0, stream,
                     xh, wt, qkv, bq, bk, bv);
  hipLaunchKernelGGL(tr_v_kernel, dim3(32, 2, 32), dim3(256), 0, stream,
                     qkv + (size_t)2 * 8388608, vtb);
  hipLaunchKernelGGL(attn_kernel, dim3(16, 32), dim3(256), 0, stream,
                     qkv, qkv + (size_t)8388608, vtb, oatt);
  hipLaunchKernelGGL(gemm_out_kernel, dim3(16, 32), dim3(256), 0, stream,
                     oatt, wt + (size_t)3 * 4194304, outp, bo);
}